// Round 3
// baseline (3886.707 us; speedup 1.0000x reference)
//
#include <hip/hip_runtime.h>

typedef float  f4v __attribute__((ext_vector_type(4)));
typedef short  s8v __attribute__((ext_vector_type(8)));

#define B_   64
#define L_   128
#define T_   255
#define RMAX 127
#define NB   64      // scan blocks

__device__ __forceinline__ unsigned short f2bf(float f) {
    union { float f; unsigned int u; } v; v.f = f;
    unsigned int u = v.u;
    unsigned int r = u + 0x7fffu + ((u >> 16) & 1u);
    return (unsigned short)(r >> 16);
}
__device__ __forceinline__ float bf2f(unsigned short s) {
    union { unsigned int u; float f; } v; v.u = ((unsigned int)s) << 16;
    return v.f;
}
__device__ __forceinline__ float sigf(float x) { return 1.f / (1.f + expf(-x)); }

// ---------------- conversion ----------------
__global__ void k_cvt_bf16(const float* __restrict__ in, unsigned short* __restrict__ out, long n4) {
    long i = blockIdx.x * (long)blockDim.x + threadIdx.x;
    if (i >= n4) return;
    float4 v = ((const float4*)in)[i];
    ushort4 o;
    o.x = f2bf(v.x); o.y = f2bf(v.y); o.z = f2bf(v.z); o.w = f2bf(v.w);
    ((ushort4*)out)[i] = o;
}

// in [K][N] fp32 -> out [N][K] bf16
__global__ void k_transpose_bf16(const float* __restrict__ in, unsigned short* __restrict__ out, int K, int N) {
    __shared__ float tile[32][33];
    int n0 = blockIdx.x * 32, k0 = blockIdx.y * 32;
    int tx = threadIdx.x, ty = threadIdx.y;   // 32 x 8
    for (int i = ty; i < 32; i += 8) tile[i][tx] = in[(size_t)(k0 + i) * N + n0 + tx];
    __syncthreads();
    for (int i = ty; i < 32; i += 8) out[(size_t)(n0 + i) * K + k0 + tx] = f2bf(tile[tx][i]);
}

// ---------------- pack Wr_l (gates 0..3) into per-block swizzled LDS image ----------------
// unit u: kgs = u&127, c = (u>>7)&63, bid = u>>13
// content = Wrt[(c>>4)*1024 + bid*16 + (c&15)][ (kgs^(c&7))*8 .. +8 ]   (left half k<1024)
__global__ void k_pack_wrl(const unsigned short* __restrict__ wrt, unsigned short* __restrict__ wrlp) {
    int u = blockIdx.x * 256 + threadIdx.x;       // 64*64*128 = 524288 units
    int kgs = u & 127;
    int c   = (u >> 7) & 63;
    int bid = u >> 13;
    int gcol = (c >> 4) * 1024 + bid * 16 + (c & 15);
    int kg = kgs ^ (c & 7);
    *(s8v*)(wrlp + (size_t)u * 8) = *(const s8v*)(wrt + (size_t)gcol * 2048 + kg * 8);
}

// ---------------- control ----------------
__global__ void k_control(const int* __restrict__ tr, int* __restrict__ desc, int* __restrict__ flags) {
    if (threadIdx.x != 0 || blockIdx.x != 0) return;
    int stack[140];
    int sp = 0, bp = 0, r = 0;
    for (int t = 0; t < T_; ++t) {
        int a = tr[t];
        if (a == 1) {
            if (bp < L_) { stack[sp++] = bp; bp++; }
        } else if (a == 2) {
            if (sp >= 2) {
                int right = stack[sp - 1], left = stack[sp - 2];
                sp -= 2;
                desc[2 + r] = left;
                desc[2 + RMAX + r] = right;
                stack[sp++] = -(r + 1);
                r++;
            }
        }
    }
    desc[0] = r;
    desc[1] = (sp > 0) ? stack[sp - 1] : 0;
    for (int i = 0; i < NB; ++i) flags[i] = 0;
}

// ---------------- word projection: 128x128 tile, BK=64, LDS staged ----------------
__global__ __launch_bounds__(256) void k_proj2(const unsigned short* __restrict__ sb,
                                               const unsigned short* __restrict__ wwt,
                                               const float* __restrict__ bw,
                                               unsigned short* __restrict__ hw,
                                               float* __restrict__ cw) {
    __shared__ unsigned short lA[128 * 64];
    __shared__ unsigned short lB[128 * 64];
    int tid = threadIdx.x, wv = tid >> 6, lane = tid & 63;
    int lr = lane & 15, lq = lane >> 4;
    int wr = wv >> 1, wc = wv & 1;
    int rb = blockIdx.y * 128, cb = blockIdx.x * 128;
    f4v acc[4][4];
    #pragma unroll
    for (int i = 0; i < 4; ++i)
        #pragma unroll
        for (int j = 0; j < 4; ++j) acc[i][j] = (f4v){0.f, 0.f, 0.f, 0.f};

    for (int ks = 0; ks < 1024; ks += 64) {
        #pragma unroll
        for (int t = 0; t < 4; ++t) {
            int p = t * 256 + tid;
            int row = p >> 3, kgs = p & 7, kg = kgs ^ (row & 7);
            *(s8v*)(lA + (size_t)p * 8) = *(const s8v*)(sb  + (size_t)(rb + row) * 1024 + ks + kg * 8);
            *(s8v*)(lB + (size_t)p * 8) = *(const s8v*)(wwt + (size_t)(cb + row) * 1024 + ks + kg * 8);
        }
        __syncthreads();
        #pragma unroll
        for (int s = 0; s < 2; ++s) {
            int kgx = (s * 4 + lq) ^ (lr & 7);
            s8v a[4], b[4];
            #pragma unroll
            for (int i = 0; i < 4; ++i) {
                int rowa = wr * 64 + i * 16 + lr;
                int rowb = wc * 64 + i * 16 + lr;
                a[i] = *(const s8v*)(lA + (size_t)(rowa * 8 + kgx) * 8);
                b[i] = *(const s8v*)(lB + (size_t)(rowb * 8 + kgx) * 8);
            }
            #pragma unroll
            for (int i = 0; i < 4; ++i)
                #pragma unroll
                for (int j = 0; j < 4; ++j)
                    acc[i][j] = __builtin_amdgcn_mfma_f32_16x16x32_bf16(a[i], b[j], acc[i][j], 0, 0, 0);
        }
        __syncthreads();
    }
    bool isH = (cb < 1024);
    #pragma unroll
    for (int j = 0; j < 4; ++j) {
        int col = cb + wc * 64 + j * 16 + lr;
        float bias = bw[col];
        #pragma unroll
        for (int i = 0; i < 4; ++i) {
            #pragma unroll
            for (int jj = 0; jj < 4; ++jj) {
                int m = rb + wr * 64 + i * 16 + lq * 4 + jj;
                float v = acc[i][j][jj] + bias;
                if (isH) hw[(size_t)m * 1024 + col] = f2bf(v);
                else     cw[(size_t)m * 1024 + (col - 1024)] = v;
            }
        }
    }
}

// ---------------- PW precompute: word-side gate contributions + br ----------------
// PW[r][m][5120] bf16 = br + sum over sides with word src of h_word @ Wr_side
// grid: (40 ntiles of 128 cols) x (64 r-pairs); tile M=128 (2 r's) x N=128, K-chunks skipped per side
__global__ __launch_bounds__(256) void k_pw(const int* __restrict__ desc,
                                            const unsigned short* __restrict__ hw,
                                            const unsigned short* __restrict__ wrt,
                                            const float* __restrict__ br,
                                            unsigned short* __restrict__ pwb) {
    __shared__ unsigned short lA[128 * 64];
    __shared__ unsigned short lB[128 * 64];
    int tid = threadIdx.x, wv = tid >> 6, lane = tid & 63;
    int lr = lane & 15, lq = lane >> 4;
    int wr = wv >> 1, wc = wv & 1;
    int cb = blockIdx.x * 128;
    int r0 = blockIdx.y * 2;
    int nred = desc[0];
    int s0[2], s1[2];
    s0[0] = (r0 < nred) ? desc[2 + r0] : -1;
    s0[1] = (r0 < nred) ? desc[2 + RMAX + r0] : -1;
    s1[0] = (r0 + 1 < nred) ? desc[2 + r0 + 1] : -1;
    s1[1] = (r0 + 1 < nred) ? desc[2 + RMAX + r0 + 1] : -1;
    bool need[2];
    need[0] = (s0[0] >= 0) || (s1[0] >= 0);
    need[1] = (s0[1] >= 0) || (s1[1] >= 0);

    f4v acc[4][4];
    #pragma unroll
    for (int i = 0; i < 4; ++i)
        #pragma unroll
        for (int j = 0; j < 4; ++j) acc[i][j] = (f4v){0.f, 0.f, 0.f, 0.f};

    for (int c = 0; c < 32; ++c) {
        int side = c >> 4;
        if (!need[side]) continue;
        int kloc = (c & 15) * 64;
        #pragma unroll
        for (int t = 0; t < 4; ++t) {
            int p = t * 256 + tid;
            int row = p >> 3, kgs = p & 7, kg = kgs ^ (row & 7);
            int m = row & 63;
            int src = (row >> 6) ? s1[side] : s0[side];
            s8v va = (s8v){0,0,0,0,0,0,0,0};
            if (src >= 0)
                va = *(const s8v*)(hw + (size_t)(m * L_ + src) * 1024 + kloc + kg * 8);
            *(s8v*)(lA + (size_t)p * 8) = va;
            *(s8v*)(lB + (size_t)p * 8) = *(const s8v*)(wrt + (size_t)(cb + row) * 2048 + side * 1024 + kloc + kg * 8);
        }
        __syncthreads();
        #pragma unroll
        for (int s = 0; s < 2; ++s) {
            int kgx = (s * 4 + lq) ^ (lr & 7);
            s8v a[4], b[4];
            #pragma unroll
            for (int i = 0; i < 4; ++i) {
                int rowa = wr * 64 + i * 16 + lr;
                int rowb = wc * 64 + i * 16 + lr;
                a[i] = *(const s8v*)(lA + (size_t)(rowa * 8 + kgx) * 8);
                b[i] = *(const s8v*)(lB + (size_t)(rowb * 8 + kgx) * 8);
            }
            #pragma unroll
            for (int i = 0; i < 4; ++i)
                #pragma unroll
                for (int j = 0; j < 4; ++j)
                    acc[i][j] = __builtin_amdgcn_mfma_f32_16x16x32_bf16(a[i], b[j], acc[i][j], 0, 0, 0);
        }
        __syncthreads();
    }
    #pragma unroll
    for (int j = 0; j < 4; ++j) {
        int col = cb + wc * 64 + j * 16 + lr;
        float bias = br[col];
        #pragma unroll
        for (int i = 0; i < 4; ++i) {
            #pragma unroll
            for (int jj = 0; jj < 4; ++jj) {
                int prow = wr * 64 + i * 16 + lq * 4 + jj;
                int rr = r0 + (prow >> 6), m = prow & 63;
                if (rr < nred)
                    pwb[((size_t)rr * B_ + m) * 5120 + col] = f2bf(acc[i][j][jj] + bias);
            }
        }
    }
}

// ---------------- persistent scan ----------------
// 64 blocks x 256 thr. Block bid owns channels [bid*16, bid*16+16).
// LDS: Wr_l gates 0..3 for its 16 ch (128KB, resident all steps) + 21KB gate scratch.
// wave w: gate w from LDS; wave 3 also gate 4 with B streamed from global Wrt.
__global__ __launch_bounds__(256, 1) void k_scan(const int* __restrict__ desc,
                                                 const float* __restrict__ cw,
                                                 const unsigned short* __restrict__ wrlp,
                                                 const unsigned short* __restrict__ wrt,
                                                 const unsigned short* __restrict__ pwb,
                                                 unsigned short* __restrict__ nhb,
                                                 float* __restrict__ nc,
                                                 int* __restrict__ flags) {
    __shared__ unsigned short lB[64 * 1024];   // 128KB
    __shared__ float scr[5 * 64 * 17];         // 21.25KB padded gate scratch
    int tid = threadIdx.x, wv = tid >> 6, lane = tid & 63;
    int lr = lane & 15, lq = lane >> 4;
    int bid = blockIdx.x;
    int nred = desc[0];
    // stage resident B
    {
        const s8v* src = (const s8v*)(wrlp + (size_t)bid * 65536);
        for (int t = 0; t < 32; ++t) {
            int p = t * 256 + tid;
            ((s8v*)lB)[p] = src[p];
        }
    }
    __syncthreads();
    int ch = bid * 16 + lr;
    int ncf = (wv == 3) ? 2 : 1;

    for (int r = 0; r < nred; ++r) {
        int ls = desc[2 + r], rs = desc[2 + RMAX + r];
        f4v acc[2][4];
        #pragma unroll
        for (int cf = 0; cf < 2; ++cf) {
            int g = cf ? 4 : wv;
            #pragma unroll
            for (int rf = 0; rf < 4; ++rf) {
                #pragma unroll
                for (int j = 0; j < 4; ++j) {
                    float v = 0.f;
                    if (cf < ncf)
                        v = bf2f(pwb[((size_t)r * B_ + rf * 16 + lq * 4 + j) * 5120 + g * 1024 + ch]);
                    acc[cf][rf][j] = v;
                }
            }
        }
        // node-left: B gates 0..3 from LDS, gate 4 from global Wrt (left half)
        if (ls < 0) {
            const unsigned short* abase = nhb + ((size_t)(-1 - ls) * B_) * 1024;
            for (int kc = 0; kc < 4; ++kc) {
                s8v a[4][8];
                #pragma unroll
                for (int rf = 0; rf < 4; ++rf)
                    #pragma unroll
                    for (int k8 = 0; k8 < 8; ++k8)
                        a[rf][k8] = *(const s8v*)(abase + (size_t)(rf * 16 + lr) * 1024 + (kc * 8 + k8) * 32 + lq * 8);
                #pragma unroll
                for (int k8 = 0; k8 < 8; ++k8) {
                    int kk = kc * 8 + k8;
                    s8v b0 = *(const s8v*)(lB + ((size_t)(wv * 16 + lr) * 128 + ((kk * 4 + lq) ^ (lr & 7))) * 8);
                    s8v b1 = b0;
                    if (wv == 3)
                        b1 = *(const s8v*)(wrt + (size_t)(4096 + bid * 16 + lr) * 2048 + kk * 32 + lq * 8);
                    #pragma unroll
                    for (int rf = 0; rf < 4; ++rf) {
                        acc[0][rf] = __builtin_amdgcn_mfma_f32_16x16x32_bf16(a[rf][k8], b0, acc[0][rf], 0, 0, 0);
                        if (wv == 3)
                            acc[1][rf] = __builtin_amdgcn_mfma_f32_16x16x32_bf16(a[rf][k8], b1, acc[1][rf], 0, 0, 0);
                    }
                }
            }
        }
        // node-right (generic fallback): all B from global Wrt (right half)
        if (rs < 0) {
            const unsigned short* abase = nhb + ((size_t)(-1 - rs) * B_) * 1024;
            for (int kc = 0; kc < 4; ++kc) {
                s8v a[4][8];
                #pragma unroll
                for (int rf = 0; rf < 4; ++rf)
                    #pragma unroll
                    for (int k8 = 0; k8 < 8; ++k8)
                        a[rf][k8] = *(const s8v*)(abase + (size_t)(rf * 16 + lr) * 1024 + (kc * 8 + k8) * 32 + lq * 8);
                #pragma unroll
                for (int k8 = 0; k8 < 8; ++k8) {
                    int kk = kc * 8 + k8;
                    s8v b0 = *(const s8v*)(wrt + (size_t)(wv * 1024 + bid * 16 + lr) * 2048 + 1024 + kk * 32 + lq * 8);
                    s8v b1 = b0;
                    if (wv == 3)
                        b1 = *(const s8v*)(wrt + (size_t)(4096 + bid * 16 + lr) * 2048 + 1024 + kk * 32 + lq * 8);
                    #pragma unroll
                    for (int rf = 0; rf < 4; ++rf) {
                        acc[0][rf] = __builtin_amdgcn_mfma_f32_16x16x32_bf16(a[rf][k8], b0, acc[0][rf], 0, 0, 0);
                        if (wv == 3)
                            acc[1][rf] = __builtin_amdgcn_mfma_f32_16x16x32_bf16(a[rf][k8], b1, acc[1][rf], 0, 0, 0);
                    }
                }
            }
        }
        // exchange gates via scratch
        #pragma unroll
        for (int cf = 0; cf < 2; ++cf) {
            if (cf < ncf) {
                int g = cf ? 4 : wv;
                #pragma unroll
                for (int rf = 0; rf < 4; ++rf)
                    #pragma unroll
                    for (int j = 0; j < 4; ++j)
                        scr[(g * 64 + rf * 16 + lq * 4 + j) * 17 + lr] = acc[cf][rf][j];
            }
        }
        __syncthreads();
        // epilogue: 4 outputs per thread
        #pragma unroll
        for (int e = 0; e < 4; ++e) {
            int idx = e * 256 + tid;
            int m = idx >> 4, ci = idx & 15;
            int chh = bid * 16 + ci;
            float g0 = scr[(0 * 64 + m) * 17 + ci];
            float g1 = scr[(1 * 64 + m) * 17 + ci];
            float g2 = scr[(2 * 64 + m) * 17 + ci];
            float g3 = scr[(3 * 64 + m) * 17 + ci];
            float g4 = scr[(4 * 64 + m) * 17 + ci];
            float lc = (ls >= 0) ? cw[(size_t)(m * L_ + ls) * 1024 + chh]
                                 : nc[((size_t)((-1 - ls) * B_ + m)) * 1024 + chh];
            float rc = (rs >= 0) ? cw[(size_t)(m * L_ + rs) * 1024 + chh]
                                 : nc[((size_t)((-1 - rs) * B_ + m)) * 1024 + chh];
            float cn = sigf(g1) * lc + sigf(g2) * rc + sigf(g0) * tanhf(g4);
            float hn = sigf(g3) * tanhf(cn);
            size_t o = ((size_t)r * B_ + m) * 1024 + chh;
            nc[o] = cn;
            nhb[o] = f2bf(hn);
        }
        // grid barrier (release writes, acquire reads; device scope)
        __syncthreads();
        if (wv == 0) {
            if (tid == 0)
                __hip_atomic_store(&flags[bid], r + 1, __ATOMIC_RELEASE, __HIP_MEMORY_SCOPE_AGENT);
            while (!__all(__hip_atomic_load(&flags[lane], __ATOMIC_ACQUIRE, __HIP_MEMORY_SCOPE_AGENT) >= r + 1))
                __builtin_amdgcn_s_sleep(4);
        }
        __syncthreads();
    }
}

// ---------------- final ----------------
__global__ void k_final(const int* __restrict__ desc,
                        const unsigned short* __restrict__ hw,
                        const unsigned short* __restrict__ nhb,
                        float* __restrict__ out) {
    int idx = blockIdx.x * 256 + threadIdx.x;
    if (idx >= B_ * 1024) return;
    int m = idx >> 10, ch = idx & 1023;
    int fs = desc[1];
    const unsigned short* src = (fs >= 0)
        ? hw  + ((size_t)(m * L_ + fs) << 10) + ch
        : nhb + ((size_t)((-1 - fs) * B_ + m) << 10) + ch;
    out[idx] = bf2f(*src);
}

extern "C" void kernel_launch(void* const* d_in, const int* in_sizes, int n_in,
                              void* d_out, int out_size, void* d_ws, size_t ws_size,
                              hipStream_t stream) {
    const float* sentence = (const float*)d_in[0];
    const int*   trans    = (const int*)d_in[1];
    const float* Ww       = (const float*)d_in[2];
    const float* bw       = (const float*)d_in[3];
    const float* Wr       = (const float*)d_in[4];
    const float* br       = (const float*)d_in[5];
    float* out = (float*)d_out;

    char* w = (char*)d_ws;
    size_t off = 0;
    unsigned short* Wrt  = (unsigned short*)(w + off); off += (size_t)5120 * 2048 * 2;      // 21.0 MB
    unsigned short* Wwt  = (unsigned short*)(w + off); off += (size_t)2048 * 1024 * 2;      //  4.2 MB
    unsigned short* WrlP = (unsigned short*)(w + off); off += (size_t)NB * 64 * 128 * 8 * 2; // 8.4 MB
    unsigned short* sb   = (unsigned short*)(w + off); off += (size_t)8192 * 1024 * 2;      // 16.8 MB
    unsigned short* hw   = (unsigned short*)(w + off); off += (size_t)8192 * 1024 * 2;      // 16.8 MB
    float*          cw   = (float*)(w + off);          off += (size_t)8192 * 1024 * 4;      // 33.6 MB
    unsigned short* nhb  = (unsigned short*)(w + off); off += (size_t)RMAX * B_ * 1024 * 2; // 16.6 MB
    float*          nc   = (float*)(w + off);          off += (size_t)RMAX * B_ * 1024 * 4; // 33.3 MB
    unsigned short* pwb  = (unsigned short*)(w + off); off += (size_t)RMAX * B_ * 5120 * 2; // 83.2 MB
    int*            desc = (int*)(w + off);            off += 1024;
    int*            flags = (int*)(w + off);           off += 1024;

    {
        long n4 = (long)8192 * 1024 / 4;
        k_cvt_bf16<<<dim3((unsigned)((n4 + 255) / 256)), dim3(256), 0, stream>>>(sentence, sb, n4);
    }
    k_transpose_bf16<<<dim3(2048 / 32, 1024 / 32), dim3(32, 8), 0, stream>>>(Ww, Wwt, 1024, 2048);
    k_transpose_bf16<<<dim3(5120 / 32, 2048 / 32), dim3(32, 8), 0, stream>>>(Wr, Wrt, 2048, 5120);
    k_pack_wrl<<<dim3(2048), dim3(256), 0, stream>>>(Wrt, WrlP);
    k_control<<<dim3(1), dim3(1), 0, stream>>>(trans, desc, flags);
    k_proj2<<<dim3(16, 64), dim3(256), 0, stream>>>(sb, Wwt, bw, hw, cw);
    k_pw<<<dim3(40, 64), dim3(256), 0, stream>>>(desc, hw, Wrt, br, pwb);
    k_scan<<<dim3(NB), dim3(256), 0, stream>>>(desc, cw, WrlP, Wrt, pwb, nhb, nc, flags);
    k_final<<<dim3((B_ * 1024 + 255) / 256), dim3(256), 0, stream>>>(desc, hw, nhb, out);
}